// Round 7
// baseline (11.918 us; speedup 1.0000x reference)
//
#include <hip/hip_runtime.h>

#define EPSF 1e-4f
#define H    256
#define W    256
#define HO   248           // valid output dim: 256 - 9 + 1
#define OW   48            // output columns per block
#define OH   16            // output rows per block
#define PC   56            // pixel columns per block = OW + 8
#define CSTR 60            // LDS row stride: 240 B rows -> 16B-aligned b128 reads
#define GX   6             // 6*48 = 288 >= 248
#define GY   16            // 16*16 = 256 >= 248
#define NBLK (GX*GY)       // 96 partials per batch

// Separable NCC.
// Phase 1 (112 of 128 threads): each thread owns pixel column c and 8 output
//   rows; 16-row register slide produces vertical 9-window sums of
//   (a, b, a2, b2, ab) -> LDS.
// Phase 2 (96 threads): 8-output horizontal slide per thread; 16-float window
//   slices read as 4x ds_read_b128; finalize NCC; block reduce -> partial.
__global__ __launch_bounds__(128) void ncc_kernel(
    const float* __restrict__ x1, const float* __restrict__ x2,
    float* __restrict__ ws)
{
    __shared__ __align__(16) float C[5][OH][CSTR];   // 19200 B
    __shared__ float warp_part[2];

    const int b  = blockIdx.z;
    const int j0 = blockIdx.x * OW;
    const int i0 = blockIdx.y * OH;
    const int tid = threadIdx.x;

    const float* p1 = x1 + (size_t)b * (H * W);
    const float* p2 = x2 + (size_t)b * (H * W);

    // ---------------- Phase 1: vertical column sums ----------------
    if (tid < 112) {
        const int c = tid % PC;        // 0..55
        const int g = tid / PC;        // 0..1, each covers 8 output rows
        const int j = j0 + c;
        const bool jok = (j < W);
        const int ibase = i0 + g * 8;

        float av[16], bv[16];
        #pragma unroll
        for (int r = 0; r < 16; ++r) {
            const int i = ibase + r;
            const bool ok = jok && (i < H);
            av[r] = ok ? p1[i * W + j] : 0.0f;
            bv[r] = ok ? p2[i * W + j] : 0.0f;
        }

        float s1 = 0.0f, s2 = 0.0f, s11 = 0.0f, s22 = 0.0f, s12 = 0.0f;
        #pragma unroll
        for (int r = 0; r < 9; ++r) {
            s1 += av[r];
            s2 += bv[r];
            s11 = fmaf(av[r], av[r], s11);
            s22 = fmaf(bv[r], bv[r], s22);
            s12 = fmaf(av[r], bv[r], s12);
        }
        const int t0 = g * 8;
        C[0][t0][c] = s1;  C[1][t0][c] = s2;
        C[2][t0][c] = s11; C[3][t0][c] = s22; C[4][t0][c] = s12;

        #pragma unroll
        for (int tt = 1; tt < 8; ++tt) {
            const float an = av[tt + 8], bn = bv[tt + 8];
            const float ao = av[tt - 1], bo = bv[tt - 1];
            s1 += an - ao;
            s2 += bn - bo;
            s11 = fmaf(an, an, s11); s11 = fmaf(-ao, ao, s11);
            s22 = fmaf(bn, bn, s22); s22 = fmaf(-bo, bo, s22);
            s12 = fmaf(an, bn, s12); s12 = fmaf(-ao, bo, s12);
            const int t = t0 + tt;
            C[0][t][c] = s1;  C[1][t][c] = s2;
            C[2][t][c] = s11; C[3][t][c] = s22; C[4][t][c] = s12;
        }
    }
    __syncthreads();

    // ---------------- Phase 2: horizontal sliding window ----------------
    // thread -> (output row t = tid/6, column group jg = tid%6 of 8 outputs)
    // jc0 = 8*jg -> 32B offsets, rows 240B -> every float4 load 16B-aligned.
    float contrib = 0.0f;
    if (tid < 96) {
        const int t   = tid / 6;       // 0..15
        const int jg  = tid - t * 6;   // 0..5
        const int jc0 = jg * 8;
        const int t_out = i0 + t;

        float Wq[8][5];
        #pragma unroll
        for (int q = 0; q < 5; ++q) {
            const float4* rp = reinterpret_cast<const float4*>(&C[q][t][jc0]);
            float cv[16];
            #pragma unroll
            for (int k4 = 0; k4 < 4; ++k4) {
                const float4 v4 = rp[k4];
                cv[k4 * 4 + 0] = v4.x; cv[k4 * 4 + 1] = v4.y;
                cv[k4 * 4 + 2] = v4.z; cv[k4 * 4 + 3] = v4.w;
            }
            float w = cv[0];
            #pragma unroll
            for (int k = 1; k < 9; ++k) w += cv[k];
            Wq[0][q] = w;
            #pragma unroll
            for (int m = 1; m < 8; ++m)
                Wq[m][q] = Wq[m - 1][q] - cv[m - 1] + cv[m + 8];
        }

        const float inv_n = 1.0f / 81.0f;
        #pragma unroll
        for (int m = 0; m < 8; ++m) {
            const int j_out = j0 + jc0 + m;
            if (t_out < HO && j_out < HO) {
                const float s1  = Wq[m][0], s2  = Wq[m][1];
                const float s11 = Wq[m][2], s22 = Wq[m][3], s12 = Wq[m][4];
                const float mu1 = s1 * inv_n;
                const float mu2 = s2 * inv_n;
                const float v1  = fmaf(-mu1, mu1, s11 * inv_n) + EPSF;
                const float v2  = fmaf(-mu2, mu2, s22 * inv_n) + EPSF;
                const float cross = fmaf(-mu1, s2, s12);
                contrib += cross * rsqrtf(v1 * v2);
            }
        }
    }

    // ---------------- block reduce -> one partial per block ----------------
    #pragma unroll
    for (int off = 32; off >= 1; off >>= 1)
        contrib += __shfl_down(contrib, off, 64);

    const int lane = tid & 63;
    const int wid  = tid >> 6;
    if (lane == 0) warp_part[wid] = contrib;
    __syncthreads();

    if (tid == 0) {
        const int blk = blockIdx.y * GX + blockIdx.x;
        ws[b * NBLK + blk] = warp_part[0] + warp_part[1];
    }
}

// Stage 2: sum NBLK partials per batch, scale, write out[b]. Overwrites out
// fully every call (no memset needed).
__global__ __launch_bounds__(128) void ncc_reduce_kernel(
    const float* __restrict__ ws, float* __restrict__ out)
{
    const int b   = blockIdx.x;
    const int tid = threadIdx.x;

    float v = (tid < NBLK) ? ws[b * NBLK + tid] : 0.0f;

    #pragma unroll
    for (int off = 32; off >= 1; off >>= 1)
        v += __shfl_down(v, off, 64);

    __shared__ float wp[2];
    const int lane = tid & 63;
    const int wv   = tid >> 6;
    if (lane == 0) wp[wv] = v;
    __syncthreads();

    if (tid == 0) {
        const float scale = 1.0f / (81.0f * (float)HO * (float)HO);
        out[b] = (wp[0] + wp[1]) * scale;
    }
}

extern "C" void kernel_launch(void* const* d_in, const int* in_sizes, int n_in,
                              void* d_out, int out_size, void* d_ws, size_t ws_size,
                              hipStream_t stream) {
    const float* x1 = (const float*)d_in[0];
    const float* x2 = (const float*)d_in[1];
    float* out = (float*)d_out;
    float* ws  = (float*)d_ws;   // 8 * 96 floats used

    dim3 block(128);
    dim3 grid(GX, GY, 8);        // 6 x 16 x 8 = 768 blocks
    ncc_kernel<<<grid, block, 0, stream>>>(x1, x2, ws);
    ncc_reduce_kernel<<<dim3(8), dim3(128), 0, stream>>>(ws, out);
}